// Round 4
// baseline (1686.734 us; speedup 1.0000x reference)
//
#include <hip/hip_runtime.h>
#include <math.h>

#define NN 50000
#define EE 800000
#define INF_ 64
#define HH 128
#define LL 3
#define CC 4
#define KK 32
#define OPS_ 7
#define BB 512
#define OUTD 10
#define DD 1024   // 2*H*(L+1)

typedef __attribute__((ext_vector_type(8))) short bf16x8_t;
typedef __attribute__((ext_vector_type(4))) float f32x4_t;
typedef __attribute__((ext_vector_type(16))) float f32x16_t;

static __device__ inline unsigned short f2bf(float f) {
    unsigned int u = __float_as_uint(f);
    unsigned int r = (u + 0x7fffu + ((u >> 16) & 1u)) >> 16;
    return (unsigned short)r;
}
static __device__ inline unsigned int pack2(float x, float y) {
    return (unsigned int)f2bf(x) | ((unsigned int)f2bf(y) << 16);
}

// ---------------- lin1 + elu : x[N,64] @ W[64,128] + b, elu ----------------
__global__ __launch_bounds__(256) void k_lin1(const float* __restrict__ x,
                                              const float* __restrict__ W,
                                              const float* __restrict__ b,
                                              float* __restrict__ xout) {
    __shared__ float sW[INF_ * HH];
    __shared__ float sb[HH];
    for (int i = threadIdx.x; i < INF_ * HH; i += 256) sW[i] = W[i];
    if (threadIdx.x < HH) sb[threadIdx.x] = b[threadIdx.x];
    __syncthreads();
    int wave = threadIdx.x >> 6, lane = threadIdx.x & 63;
    int base = blockIdx.x * 64;
    for (int i = 0; i < 16; ++i) {
        int n = base + wave * 16 + i;
        if (n >= NN) break;
        float xv = x[n * INF_ + lane];
        float acc0 = sb[lane], acc1 = sb[lane + 64];
        #pragma unroll 8
        for (int h = 0; h < INF_; ++h) {
            float s = __shfl(xv, h, 64);
            acc0 += s * sW[h * HH + lane];
            acc1 += s * sW[h * HH + lane + 64];
        }
        xout[n * HH + lane]      = acc0 > 0.f ? acc0 : expm1f(acc0);
        xout[n * HH + lane + 64] = acc1 > 0.f ? acc1 : expm1f(acc1);
    }
}

// ---------------- degree count ----------------
__global__ void k_deg(const int* __restrict__ dst, int* __restrict__ deg) {
    int e = blockIdx.x * 256 + threadIdx.x;
    if (e < EE) atomicAdd(&deg[dst[e]], 1);
}

// ---------------- CSR offset alloc (order-free) + degc/dinv ----------------
__global__ void k_alloc(const int* __restrict__ deg, int* __restrict__ off,
                        int* __restrict__ gcount, float* __restrict__ degc,
                        float* __restrict__ dinv) {
    int n = blockIdx.x * 256 + threadIdx.x;
    if (n < NN) {
        int d = deg[n];
        off[n] = atomicAdd(gcount, d);
        float dc = fmaxf((float)d, 1.0f);
        degc[n] = dc;
        dinv[n] = rsqrtf(dc);
    }
}

// ---------------- CSR fill ----------------
__global__ void k_csrfill(const int* __restrict__ src, const int* __restrict__ dst,
                          const int* __restrict__ off, int* __restrict__ cursor,
                          int* __restrict__ csr_src) {
    int e = blockIdx.x * 256 + threadIdx.x;
    if (e < EE) {
        int d = dst[e];
        int p = atomicAdd(&cursor[d], 1);
        csr_src[off[d] + p] = src[e];
    }
}

// ---------------- graph offsets from sorted batch ----------------
__global__ void k_goff(const int* __restrict__ batch, int* __restrict__ goff) {
    int i = blockIdx.x * 256 + threadIdx.x;
    if (i >= NN) return;
    int b = batch[i];
    if (i == 0) { for (int g = 0; g <= b; ++g) goff[g] = 0; }
    else {
        int bp = batch[i - 1];
        for (int g = bp + 1; g <= b; ++g) goff[g] = i;
    }
    if (i == NN - 1) { for (int g = b + 1; g <= BB; ++g) goff[g] = NN; }
}

// ---------------- vn init ----------------
__global__ void k_vninit(const float* __restrict__ vn0, float* __restrict__ vn) {
    int i = blockIdx.x * 256 + threadIdx.x;
    if (i < BB * HH) vn[i] = vn0[i & (HH - 1)];
}

// ---------------- x += vn[batch]; a0x/a1x dot products ----------------
__global__ __launch_bounds__(256) void k_addvn_dots(float* __restrict__ x,
                                                    const float* __restrict__ vn,
                                                    const int* __restrict__ batch,
                                                    const float* __restrict__ att,
                                                    float* __restrict__ a0x,
                                                    float* __restrict__ a1x) {
    int wave = threadIdx.x >> 6, lane = threadIdx.x & 63;
    int n = blockIdx.x * 4 + wave;
    if (n >= NN) return;
    int b = batch[n];
    float v0 = x[n * HH + lane]      + vn[b * HH + lane];
    float v1 = x[n * HH + lane + 64] + vn[b * HH + lane + 64];
    x[n * HH + lane] = v0;
    x[n * HH + lane + 64] = v1;
    float d0 = v0 * att[lane] + v1 * att[lane + 64];
    float d1 = v0 * att[HH + lane] + v1 * att[HH + lane + 64];
    #pragma unroll
    for (int s = 32; s; s >>= 1) { d0 += __shfl_xor(d0, s, 64); d1 += __shfl_xor(d1, s, 64); }
    if (lane == 0) { a0x[n] = d0; a1x[n] = d1; }
}

// ---- attention + aggregation; emits 6 bf16 op-input matrices [n][128] ----
__global__ __launch_bounds__(256) void k_agg(const float* __restrict__ x,
                                             const int* __restrict__ off,
                                             const int* __restrict__ deg,
                                             const int* __restrict__ csr_src,
                                             const float* __restrict__ dinv,
                                             const float* __restrict__ degc,
                                             const float* __restrict__ a0x,
                                             const float* __restrict__ a1x,
                                             unsigned int* __restrict__ An,
                                             unsigned int* __restrict__ Axs,
                                             unsigned int* __restrict__ Aat,
                                             unsigned int* __restrict__ Axm,
                                             unsigned int* __restrict__ Am,
                                             unsigned int* __restrict__ Ax) {
    int wave = threadIdx.x >> 6, lane = threadIdx.x & 63;
    int n = blockIdx.x * 4 + wave;
    if (n >= NN) return;
    int s = off[n], e = s + deg[n];
    float a1n = a1x[n];
    float dinvn = dinv[n];
    // pass 1: segment max of leaky_relu scores
    float m = -INFINITY;
    for (int j = s + lane; j < e; j += 64) {
        int ss = csr_src[j];
        float ev = a0x[ss] + a1n;
        ev = ev > 0.f ? ev : 0.2f * ev;
        m = fmaxf(m, ev);
    }
    #pragma unroll
    for (int sh = 32; sh; sh >>= 1) m = fmaxf(m, __shfl_xor(m, sh, 64));
    // pass 2: sum of exp
    float ls = 0.f;
    for (int j = s + lane; j < e; j += 64) {
        int ss = csr_src[j];
        float ev = a0x[ss] + a1n;
        ev = ev > 0.f ? ev : 0.2f * ev;
        ls += expf(ev - m);
    }
    #pragma unroll
    for (int sh = 32; sh; sh >>= 1) ls += __shfl_xor(ls, sh, 64);
    float sinv = 1.f / (ls + 1e-16f);
    // pass 3: feature aggregation; lane owns features 2*lane, 2*lane+1
    float2 as = {0.f, 0.f}, an = {0.f, 0.f}, aa = {0.f, 0.f};
    const float2* x2 = (const float2*)x;
    for (int j0 = s; j0 < e; j0 += 64) {
        int cnt = min(64, e - j0);
        int ss = (lane < cnt) ? csr_src[j0 + lane] : 0;
        float wn = dinv[ss] * dinvn;
        float ev = a0x[ss] + a1n;
        ev = ev > 0.f ? ev : 0.2f * ev;
        float wa = expf(ev - m) * sinv;
        for (int k = 0; k < cnt; ++k) {
            int sid  = __shfl(ss, k, 64);
            float wnk = __shfl(wn, k, 64);
            float wak = __shfl(wa, k, 64);
            float2 xv = x2[sid * 64 + lane];
            as.x += xv.x;        as.y += xv.y;
            an.x += wnk * xv.x;  an.y += wnk * xv.y;
            aa.x += wak * xv.x;  aa.y += wak * xv.y;
        }
    }
    float2 xv = x2[(size_t)n * 64 + lane];
    float inv_d = 1.f / degc[n];
    int idx = n * 64 + lane;
    An[idx]  = pack2(an.x, an.y);
    Axs[idx] = pack2(xv.x + as.x, xv.y + as.y);
    Aat[idx] = pack2(aa.x, aa.y);
    Axm[idx] = pack2(xv.x + as.x * inv_d, xv.y + as.y * inv_d);
    Am[idx]  = pack2(as.x * inv_d, as.y * inv_d);
    Ax[idx]  = pack2(xv.x, xv.y);
}

// ---- W_ops → A-fragment layout for mfma_32x32x16 (A = W^T):
//      wfa[((l*7+o)*4+c)*8+hs][lane][j]; m=kcol=lane&31, k=h=hs*16+(lane>>5)*8+j
__global__ void k_wprep(const float* __restrict__ Wops, unsigned short* __restrict__ wfa) {
    int idx = blockIdx.x * 256 + threadIdx.x;
    if (idx >= LL * 114688) return;
    int j = idx & 7, lane = (idx >> 3) & 63, hs = (idx >> 9) & 7;
    int c = (idx >> 12) & 3;
    int rem = idx >> 14;            // l*7+o
    int l = rem / OPS_, o = rem % OPS_;
    int h = hs * 16 + (lane >> 5) * 8 + j;
    int kcol = lane & 31;
    float v = Wops[(((size_t)(l * CC + c) * OPS_ + o) * HH + h) * KK + kcol];
    wfa[idx] = f2bf(v);
}

// ---- bias reorder [l][o][col] + premixed LN gains wgf = softmax(alpha)*ln_g ----
__global__ void k_sprep(const float* __restrict__ bops, const float* __restrict__ alphas,
                        const float* __restrict__ lng,
                        float* __restrict__ biasf, float* __restrict__ wgf) {
    int idx = blockIdx.x * 256 + threadIdx.x;
    if (idx >= LL * OPS_ * HH) return;
    int l = idx / (OPS_ * HH); int rem = idx % (OPS_ * HH);
    int o = rem / HH; int col = rem % HH;
    int c = col >> 5, kc = col & 31;
    biasf[idx] = bops[((l * CC + c) * OPS_ + o) * KK + kc];
    const float* a = alphas + (l * CC + c) * OPS_;
    float mx = -INFINITY;
    for (int o2 = 0; o2 < OPS_; ++o2) mx = fmaxf(mx, a[o2]);
    float ssum = 0.f, ev[OPS_];
    for (int o2 = 0; o2 < OPS_; ++o2) { ev[o2] = expf(a[o2] - mx); ssum += ev[o2]; }
    wgf[idx] = (ev[o] / ssum) * lng[l * HH + col];
}

// ---- MFMA op-mix: ops split across waves, 32 nodes/block, LDS fp32 merge ----
// D[m=kcol 32][n=node 32] = W^T(32x16) @ X^T(16x32) over 8 h-steps; LN over the
// 32-row m-dim: 15 in-reg adds + one shfl_xor(32). Mixed bias (= lnb, since
// softmax weights sum to 1) added once at out-stage.
__global__ __launch_bounds__(256, 4) void k_mixmm(
        const unsigned short* __restrict__ An, const unsigned short* __restrict__ Axs,
        const unsigned short* __restrict__ Aat, const unsigned short* __restrict__ Axm,
        const unsigned short* __restrict__ Am, const unsigned short* __restrict__ Ax,
        const unsigned short* __restrict__ wfa, const float* __restrict__ biasf,
        const float* __restrict__ wgf, const float* __restrict__ lnb,
        float* __restrict__ xnew, float* __restrict__ bnstat) {
    __shared__ float sMerge[32 * 129];
    __shared__ float sBias[OPS_ * HH], sWg[OPS_ * HH];
    __shared__ float sLnb[HH], sS[HH], sQ[HH];
    int t = threadIdx.x, w = t >> 6, lane = t & 63;
    int n32 = lane & 31, hi = lane >> 5;
    for (int i = t; i < OPS_ * HH; i += 256) { sBias[i] = biasf[i]; sWg[i] = wgf[i]; }
    if (t < HH) { sLnb[t] = lnb[t]; sS[t] = 0.f; sQ[t] = 0.f; }
    for (int i = t; i < 32 * 129; i += 256) sMerge[i] = 0.f;
    int nb = blockIdx.x * 32;
    size_t xrow = (size_t)min(nb + n32, NN - 1) * HH;
    const unsigned short* Aops[OPS_] = {An, Axs, Aat, Axm, Am, An, Ax};
    __syncthreads();

    #pragma unroll
    for (int oi = 0; oi < 2; ++oi) {
        int o = w + oi * 4;
        if (o >= OPS_) break;
        const unsigned short* X = Aops[o];
        bf16x8_t xf[8];
        #pragma unroll
        for (int hs = 0; hs < 8; ++hs)
            xf[hs] = *(const bf16x8_t*)(X + xrow + hs * 16 + hi * 8);
        const unsigned short* wb = wfa + (size_t)o * 4 * 8 * 512 + lane * 8;
        #pragma unroll
        for (int c = 0; c < 4; ++c) {
            f32x16_t acc;
            #pragma unroll
            for (int j = 0; j < 16; ++j) acc[j] = 0.f;
            #pragma unroll
            for (int hs = 0; hs < 8; ++hs) {
                bf16x8_t af = *(const bf16x8_t*)(wb + (c * 8 + hs) * 512);
                acc = __builtin_amdgcn_mfma_f32_32x32x16_bf16(af, xf[hs], acc, 0, 0, 0);
            }
            // LN over the 32 kcols (m-dim): reg -> row = (reg&3) + 8*(reg>>2) + 4*hi
            const float* bp = &sBias[o * HH + c * 32 + hi * 4];
            const float* gp = &sWg[o * HH + c * 32 + hi * 4];
            float yy[16];
            float s = 0.f, q = 0.f;
            #pragma unroll
            for (int jb = 0; jb < 4; ++jb) {
                float4 bv = *(const float4*)(bp + jb * 8);
                float v0 = acc[4 * jb + 0] + bv.x;
                float v1 = acc[4 * jb + 1] + bv.y;
                float v2 = acc[4 * jb + 2] + bv.z;
                float v3 = acc[4 * jb + 3] + bv.w;
                yy[4 * jb + 0] = v0; yy[4 * jb + 1] = v1;
                yy[4 * jb + 2] = v2; yy[4 * jb + 3] = v3;
                s += (v0 + v1) + (v2 + v3);
                q += v0 * v0 + v1 * v1 + v2 * v2 + v3 * v3;
            }
            s += __shfl_xor(s, 32, 64);
            q += __shfl_xor(q, 32, 64);
            float mu = s * (1.f / 32.f);
            float var = fmaxf(q * (1.f / 32.f) - mu * mu, 0.f);
            float rs = rsqrtf(var + 1e-5f);
            #pragma unroll
            for (int jb = 0; jb < 4; ++jb) {
                float4 gv = *(const float4*)(gp + jb * 8);
                float* mrow = &sMerge[n32 * 129 + c * 32 + hi * 4 + jb * 8];
                atomicAdd(&mrow[0], (yy[4 * jb + 0] - mu) * rs * gv.x);
                atomicAdd(&mrow[1], (yy[4 * jb + 1] - mu) * rs * gv.y);
                atomicAdd(&mrow[2], (yy[4 * jb + 2] - mu) * rs * gv.z);
                atomicAdd(&mrow[3], (yy[4 * jb + 3] - mu) * rs * gv.w);
            }
        }
    }
    __syncthreads();
    // out-stage (coalesced float4) + BN partial stats
    {
        int nloc = t >> 5, colb = (t & 31) * 4;
        float lb0 = sLnb[colb], lb1 = sLnb[colb + 1], lb2 = sLnb[colb + 2], lb3 = sLnb[colb + 3];
        float p0 = 0.f, p1 = 0.f, p2 = 0.f, p3 = 0.f;
        float q0 = 0.f, q1 = 0.f, q2 = 0.f, q3 = 0.f;
        #pragma unroll
        for (int pass = 0; pass < 4; ++pass) {
            int n = nloc + pass * 8;
            int gn = nb + n;
            if (gn < NN) {
                const float* mrow = &sMerge[n * 129 + colb];
                float v0 = mrow[0] + lb0, v1 = mrow[1] + lb1;
                float v2 = mrow[2] + lb2, v3 = mrow[3] + lb3;
                *(float4*)&xnew[(size_t)gn * HH + colb] = make_float4(v0, v1, v2, v3);
                p0 += v0; p1 += v1; p2 += v2; p3 += v3;
                q0 += v0 * v0; q1 += v1 * v1; q2 += v2 * v2; q3 += v3 * v3;
            }
        }
        atomicAdd(&sS[colb], p0); atomicAdd(&sS[colb + 1], p1);
        atomicAdd(&sS[colb + 2], p2); atomicAdd(&sS[colb + 3], p3);
        atomicAdd(&sQ[colb], q0); atomicAdd(&sQ[colb + 1], q1);
        atomicAdd(&sQ[colb + 2], q2); atomicAdd(&sQ[colb + 3], q3);
    }
    __syncthreads();
    if (t < HH) { atomicAdd(&bnstat[t], sS[t]); atomicAdd(&bnstat[HH + t], sQ[t]); }
}

// ---------------- BN finalize (scale/shift per feature) ----------------
__global__ void k_bnfin(const float* __restrict__ stat, const float* __restrict__ g,
                        const float* __restrict__ b, float* __restrict__ scsh,
                        float invn, int dim) {
    int t = threadIdx.x;
    if (t < dim) {
        float mean = stat[t] * invn;
        float var = fmaxf(stat[dim + t] * invn - mean * mean, 0.f);
        float sc = g[t] * rsqrtf(var + 1e-5f);
        scsh[t] = sc;
        scsh[dim + t] = b[t] - mean * sc;
    }
}

// ---------------- BN apply + per-graph pool (mean/max) + graph sum --------
__global__ void k_pool(const float* __restrict__ src, const float* __restrict__ scsh,
                       const int* __restrict__ goff, float* __restrict__ xout,
                       float* __restrict__ pooled, float* __restrict__ gsum, int slice) {
    int b = blockIdx.x;
    int f = threadIdx.x;           // 128 threads
    int s = goff[b], e = goff[b + 1];
    float sc = 1.f, sh = 0.f;
    if (scsh) { sc = scsh[f]; sh = scsh[HH + f]; }
    float fs = 0.f, fm = -INFINITY;
    for (int i = s; i < e; ++i) {
        float v = src[i * HH + f] * sc + sh;
        if (xout) xout[i * HH + f] = v;
        fs += v;
        fm = fmaxf(fm, v);
    }
    float cnt = fmaxf((float)(e - s), 1.f);
    pooled[b * DD + slice * HH + f] = fs / cnt;
    pooled[b * DD + 512 + slice * HH + f] = (e > s) ? fm : 0.f;
    if (gsum) gsum[b * HH + f] = fs;
}

// ---------------- virtual-node MLP pieces ----------------
__global__ void k_vn1(const float* __restrict__ gsum, const float* __restrict__ vn,
                      const float* __restrict__ W1, const float* __restrict__ b1,
                      float* __restrict__ h1, float* __restrict__ stat) {
    __shared__ float row[HH];
    int b = blockIdx.x, t = threadIdx.x;   // 256 threads
    if (t < HH) row[t] = gsum[b * HH + t] + vn[b * HH + t];
    __syncthreads();
    float acc = b1[t];
    for (int h = 0; h < HH; ++h) acc += row[h] * W1[h * 2 * HH + t];
    h1[b * 2 * HH + t] = acc;
    atomicAdd(&stat[t], acc);
    atomicAdd(&stat[2 * HH + t], acc * acc);
}

__global__ void k_vn2(const float* __restrict__ h1, const float* __restrict__ scsh1,
                      const float* __restrict__ W2, const float* __restrict__ b2,
                      float* __restrict__ h2, float* __restrict__ stat) {
    __shared__ float row[2 * HH];
    int b = blockIdx.x, t = threadIdx.x;   // 256 threads
    float v = h1[b * 2 * HH + t] * scsh1[t] + scsh1[2 * HH + t];
    row[t] = fmaxf(v, 0.f);
    __syncthreads();
    if (t < HH) {
        float acc = b2[t];
        for (int h = 0; h < 2 * HH; ++h) acc += row[h] * W2[h * HH + t];
        h2[b * HH + t] = acc;
        atomicAdd(&stat[t], acc);
        atomicAdd(&stat[HH + t], acc * acc);
    }
}

__global__ void k_vnout(const float* __restrict__ h2, const float* __restrict__ scsh2,
                        float* __restrict__ vn) {
    int i = blockIdx.x * 256 + threadIdx.x;
    if (i < BB * HH) {
        int f = i & (HH - 1);
        float v = h2[i] * scsh2[f] + scsh2[HH + f];
        vn[i] = fmaxf(v, 0.f);
    }
}

// ---------------- masked head ----------------
__global__ void k_head(const float* __restrict__ pooled, const float* __restrict__ W,
                       const float* __restrict__ bias, const float* __restrict__ mask,
                       float* __restrict__ out) {
    int wave = threadIdx.x >> 6, lane = threadIdx.x & 63;
    int idx = blockIdx.x * 4 + wave;
    if (idx >= BB * OUTD) return;
    int b = idx / OUTD, o = idx % OUTD;
    float acc = 0.f;
    for (int k = lane; k < DD; k += 64)
        acc += pooled[b * DD + k] * W[k * OUTD + o] * mask[k * OUTD + o];
    #pragma unroll
    for (int sh = 32; sh; sh >>= 1) acc += __shfl_xor(acc, sh, 64);
    if (lane == 0) out[idx] = acc + bias[o];
}

extern "C" void kernel_launch(void* const* d_in, const int* in_sizes, int n_in,
                              void* d_out, int out_size, void* d_ws, size_t ws_size,
                              hipStream_t stream) {
    const float* x_in   = (const float*)d_in[0];
    const int*   ei     = (const int*)d_in[1];
    const int*   batch  = (const int*)d_in[2];
    const float* lin1W  = (const float*)d_in[3];
    const float* lin1b  = (const float*)d_in[4];
    const float* vn0    = (const float*)d_in[5];
    const float* Wops   = (const float*)d_in[6];
    const float* bops   = (const float*)d_in[7];
    const float* atta   = (const float*)d_in[8];
    const float* lng    = (const float*)d_in[9];
    const float* lnb    = (const float*)d_in[10];
    const float* bng    = (const float*)d_in[11];
    const float* bnb    = (const float*)d_in[12];
    const float* vnW1   = (const float*)d_in[13];
    const float* vnb1   = (const float*)d_in[14];
    const float* vnbn1g = (const float*)d_in[15];
    const float* vnbn1b = (const float*)d_in[16];
    const float* vnW2   = (const float*)d_in[17];
    const float* vnb2   = (const float*)d_in[18];
    const float* vnbn2g = (const float*)d_in[19];
    const float* vnbn2b = (const float*)d_in[20];
    const float* alphas = (const float*)d_in[21];
    const float* headW  = (const float*)d_in[22];
    const float* headb  = (const float*)d_in[23];
    const float* headm  = (const float*)d_in[24];
    float* out = (float*)d_out;
    const int* src = ei;
    const int* dst = ei + EE;

    // ---- workspace layout (fp32 words) ----
    float* ws = (float*)d_ws;
    size_t p = 0;
    float* xcur    = ws + p; p += (size_t)NN * HH;
    float* a0x     = ws + p; p += NN;
    float* a1x     = ws + p; p += NN;
    float* degc    = ws + p; p += NN;
    float* dinv    = ws + p; p += NN;
    float* vn      = ws + p; p += BB * HH;
    float* gsum    = ws + p; p += BB * HH;
    float* h1      = ws + p; p += BB * 2 * HH;
    float* h2      = ws + p; p += BB * HH;
    float* pooled  = ws + p; p += (size_t)BB * DD;
    float* bnscsh  = ws + p; p += LL * 2 * HH;
    float* vnsc1   = ws + p; p += 2 * 2 * (2 * HH);
    float* vnsc2   = ws + p; p += 2 * 2 * HH;
    float* biasf   = ws + p; p += LL * OPS_ * HH;
    float* wgf     = ws + p; p += LL * OPS_ * HH;
    // bf16 op-input matrices: 6 x [NN][128] bf16, addressed as uint (2 bf16 each)
    unsigned int* An  = (unsigned int*)(ws + p); p += (size_t)NN * 64;
    unsigned int* Axs = (unsigned int*)(ws + p); p += (size_t)NN * 64;
    unsigned int* Aat = (unsigned int*)(ws + p); p += (size_t)NN * 64;
    unsigned int* Axm = (unsigned int*)(ws + p); p += (size_t)NN * 64;
    unsigned int* Am  = (unsigned int*)(ws + p); p += (size_t)NN * 64;
    unsigned int* Ax  = (unsigned int*)(ws + p); p += (size_t)NN * 64;
    unsigned short* wfa = (unsigned short*)(ws + p); p += (LL * 114688) / 2;
    // zeroed float region (atomic accumulators)
    float* zf = ws + p;
    float* bnstat  = ws + p; p += LL * 2 * HH;          // 768
    float* vnstat1 = ws + p; p += 2 * 2 * (2 * HH);     // 1024
    float* vnstat2 = ws + p; p += 2 * 2 * HH;           // 512
    size_t zf_cnt = (size_t)((ws + p) - zf);
    // int region
    int* ib = (int*)(ws + p);
    int* deg    = ib;                 // zeroed
    int* gcount = ib + NN;            // zeroed
    int* cursor = ib + NN + 1;        // zeroed
    size_t zi_cnt = (size_t)(2 * NN + 1);
    int* off    = ib + 2 * NN + 1;
    int* goff   = off + NN;
    int* csr    = goff + (BB + 1);

    hipMemsetAsync(zf, 0, zf_cnt * sizeof(float), stream);
    hipMemsetAsync(ib, 0, zi_cnt * sizeof(int), stream);

    // ---- graph/CSR setup + weight prep ----
    k_lin1<<<(NN + 63) / 64, 256, 0, stream>>>(x_in, lin1W, lin1b, xcur);
    k_deg<<<(EE + 255) / 256, 256, 0, stream>>>(dst, deg);
    k_alloc<<<(NN + 255) / 256, 256, 0, stream>>>(deg, off, gcount, degc, dinv);
    k_csrfill<<<(EE + 255) / 256, 256, 0, stream>>>(src, dst, off, cursor, csr);
    k_goff<<<(NN + 255) / 256, 256, 0, stream>>>(batch, goff);
    k_vninit<<<(BB * HH + 255) / 256, 256, 0, stream>>>(vn0, vn);
    k_wprep<<<(LL * 114688 + 255) / 256, 256, 0, stream>>>(Wops, wfa);
    k_sprep<<<(LL * OPS_ * HH + 255) / 256, 256, 0, stream>>>(bops, alphas, lng, biasf, wgf);
    // pool slice 0 (gr[0] = elu(lin1) x, pre-vn)
    k_pool<<<BB, HH, 0, stream>>>(xcur, nullptr, goff, nullptr, pooled, nullptr, 0);

    for (int l = 0; l < LL; ++l) {
        k_addvn_dots<<<NN / 4, 256, 0, stream>>>(xcur, vn, batch, atta + l * 2 * HH, a0x, a1x);
        k_agg<<<NN / 4, 256, 0, stream>>>(xcur, off, deg, csr, dinv, degc, a0x, a1x,
                                          An, Axs, Aat, Axm, Am, Ax);
        k_mixmm<<<(NN + 31) / 32, 256, 0, stream>>>(
            (const unsigned short*)An, (const unsigned short*)Axs,
            (const unsigned short*)Aat, (const unsigned short*)Axm,
            (const unsigned short*)Am, (const unsigned short*)Ax,
            wfa + (size_t)l * 114688, biasf + l * OPS_ * HH,
            wgf + l * OPS_ * HH, lnb + l * HH,
            xcur, bnstat + l * 2 * HH);
        k_bnfin<<<1, 128, 0, stream>>>(bnstat + l * 2 * HH, bng + l * HH, bnb + l * HH,
                                       bnscsh + l * 2 * HH, 1.0f / (float)NN, HH);
        k_pool<<<BB, HH, 0, stream>>>(xcur, bnscsh + l * 2 * HH, goff, xcur, pooled,
                                      (l < LL - 1) ? gsum : nullptr, l + 1);
        if (l < LL - 1) {
            k_vn1<<<BB, 256, 0, stream>>>(gsum, vn, vnW1 + (size_t)l * HH * 2 * HH,
                                          vnb1 + l * 2 * HH, h1, vnstat1 + l * 2 * (2 * HH));
            k_bnfin<<<1, 256, 0, stream>>>(vnstat1 + l * 2 * (2 * HH), vnbn1g + l * 2 * HH,
                                           vnbn1b + l * 2 * HH, vnsc1 + l * 2 * (2 * HH),
                                           1.0f / (float)BB, 2 * HH);
            k_vn2<<<BB, 256, 0, stream>>>(h1, vnsc1 + l * 2 * (2 * HH),
                                          vnW2 + (size_t)l * 2 * HH * HH, vnb2 + l * HH,
                                          h2, vnstat2 + l * 2 * HH);
            k_bnfin<<<1, 128, 0, stream>>>(vnstat2 + l * 2 * HH, vnbn2g + l * HH,
                                           vnbn2b + l * HH, vnsc2 + l * 2 * HH,
                                           1.0f / (float)BB, HH);
            k_vnout<<<(BB * HH + 255) / 256, 256, 0, stream>>>(h2, vnsc2 + l * 2 * HH, vn);
        }
    }
    k_head<<<(BB * OUTD) / 4, 256, 0, stream>>>(pooled, headW, headb, headm, out);
}

// Round 6
// 1118.621 us; speedup vs baseline: 1.5079x; 1.5079x over previous
//
#include <hip/hip_runtime.h>
#include <math.h>

#define NN 50000
#define EE 800000
#define INF_ 64
#define HH 128
#define LL 3
#define CC 4
#define KK 32
#define OPS_ 7
#define BB 512
#define OUTD 10
#define DD 1024   // 2*H*(L+1)

typedef __attribute__((ext_vector_type(8))) short bf16x8_t;
typedef __attribute__((ext_vector_type(4))) float f32x4_t;

static __device__ inline unsigned short f2bf(float f) {
    unsigned int u = __float_as_uint(f);
    unsigned int r = (u + 0x7fffu + ((u >> 16) & 1u)) >> 16;
    return (unsigned short)r;
}
static __device__ inline unsigned int pack2(float x, float y) {
    return (unsigned int)f2bf(x) | ((unsigned int)f2bf(y) << 16);
}

// ---------------- lin1 + elu : x[N,64] @ W[64,128] + b, elu ----------------
__global__ __launch_bounds__(256) void k_lin1(const float* __restrict__ x,
                                              const float* __restrict__ W,
                                              const float* __restrict__ b,
                                              float* __restrict__ xout) {
    __shared__ float sW[INF_ * HH];
    __shared__ float sb[HH];
    for (int i = threadIdx.x; i < INF_ * HH; i += 256) sW[i] = W[i];
    if (threadIdx.x < HH) sb[threadIdx.x] = b[threadIdx.x];
    __syncthreads();
    int wave = threadIdx.x >> 6, lane = threadIdx.x & 63;
    int base = blockIdx.x * 64;
    for (int i = 0; i < 16; ++i) {
        int n = base + wave * 16 + i;
        if (n >= NN) break;
        float xv = x[n * INF_ + lane];
        float acc0 = sb[lane], acc1 = sb[lane + 64];
        #pragma unroll 8
        for (int h = 0; h < INF_; ++h) {
            float s = __shfl(xv, h, 64);
            acc0 += s * sW[h * HH + lane];
            acc1 += s * sW[h * HH + lane + 64];
        }
        xout[n * HH + lane]      = acc0 > 0.f ? acc0 : expm1f(acc0);
        xout[n * HH + lane + 64] = acc1 > 0.f ? acc1 : expm1f(acc1);
    }
}

// ---------------- degree count ----------------
__global__ void k_deg(const int* __restrict__ dst, int* __restrict__ deg) {
    int e = blockIdx.x * 256 + threadIdx.x;
    if (e < EE) atomicAdd(&deg[dst[e]], 1);
}

// ---------------- CSR offset alloc (order-free) + degc/dinv ----------------
__global__ void k_alloc(const int* __restrict__ deg, int* __restrict__ off,
                        int* __restrict__ gcount, float* __restrict__ degc,
                        float* __restrict__ dinv) {
    int n = blockIdx.x * 256 + threadIdx.x;
    if (n < NN) {
        int d = deg[n];
        off[n] = atomicAdd(gcount, d);
        float dc = fmaxf((float)d, 1.0f);
        degc[n] = dc;
        dinv[n] = rsqrtf(dc);
    }
}

// ---------------- CSR fill ----------------
__global__ void k_csrfill(const int* __restrict__ src, const int* __restrict__ dst,
                          const int* __restrict__ off, int* __restrict__ cursor,
                          int* __restrict__ csr_src) {
    int e = blockIdx.x * 256 + threadIdx.x;
    if (e < EE) {
        int d = dst[e];
        int p = atomicAdd(&cursor[d], 1);
        csr_src[off[d] + p] = src[e];
    }
}

// ---------------- graph offsets from sorted batch ----------------
__global__ void k_goff(const int* __restrict__ batch, int* __restrict__ goff) {
    int i = blockIdx.x * 256 + threadIdx.x;
    if (i >= NN) return;
    int b = batch[i];
    if (i == 0) { for (int g = 0; g <= b; ++g) goff[g] = 0; }
    else {
        int bp = batch[i - 1];
        for (int g = bp + 1; g <= b; ++g) goff[g] = i;
    }
    if (i == NN - 1) { for (int g = b + 1; g <= BB; ++g) goff[g] = NN; }
}

// ---------------- vn init ----------------
__global__ void k_vninit(const float* __restrict__ vn0, float* __restrict__ vn) {
    int i = blockIdx.x * 256 + threadIdx.x;
    if (i < BB * HH) vn[i] = vn0[i & (HH - 1)];
}

// ---------------- x += vn[batch]; a0x/a1x dot products ----------------
__global__ __launch_bounds__(256) void k_addvn_dots(float* __restrict__ x,
                                                    const float* __restrict__ vn,
                                                    const int* __restrict__ batch,
                                                    const float* __restrict__ att,
                                                    float* __restrict__ a0x,
                                                    float* __restrict__ a1x) {
    int wave = threadIdx.x >> 6, lane = threadIdx.x & 63;
    int n = blockIdx.x * 4 + wave;
    if (n >= NN) return;
    int b = batch[n];
    float v0 = x[n * HH + lane]      + vn[b * HH + lane];
    float v1 = x[n * HH + lane + 64] + vn[b * HH + lane + 64];
    x[n * HH + lane] = v0;
    x[n * HH + lane + 64] = v1;
    float d0 = v0 * att[lane] + v1 * att[lane + 64];
    float d1 = v0 * att[HH + lane] + v1 * att[HH + lane + 64];
    #pragma unroll
    for (int s = 32; s; s >>= 1) { d0 += __shfl_xor(d0, s, 64); d1 += __shfl_xor(d1, s, 64); }
    if (lane == 0) { a0x[n] = d0; a1x[n] = d1; }
}

// ---- attention + aggregation; emits 6 bf16 op-input matrices [n][128] ----
__global__ __launch_bounds__(256) void k_agg(const float* __restrict__ x,
                                             const int* __restrict__ off,
                                             const int* __restrict__ deg,
                                             const int* __restrict__ csr_src,
                                             const float* __restrict__ dinv,
                                             const float* __restrict__ degc,
                                             const float* __restrict__ a0x,
                                             const float* __restrict__ a1x,
                                             unsigned int* __restrict__ An,
                                             unsigned int* __restrict__ Axs,
                                             unsigned int* __restrict__ Aat,
                                             unsigned int* __restrict__ Axm,
                                             unsigned int* __restrict__ Am,
                                             unsigned int* __restrict__ Ax) {
    int wave = threadIdx.x >> 6, lane = threadIdx.x & 63;
    int n = blockIdx.x * 4 + wave;
    if (n >= NN) return;
    int s = off[n], e = s + deg[n];
    float a1n = a1x[n];
    float dinvn = dinv[n];
    // pass 1: segment max of leaky_relu scores
    float m = -INFINITY;
    for (int j = s + lane; j < e; j += 64) {
        int ss = csr_src[j];
        float ev = a0x[ss] + a1n;
        ev = ev > 0.f ? ev : 0.2f * ev;
        m = fmaxf(m, ev);
    }
    #pragma unroll
    for (int sh = 32; sh; sh >>= 1) m = fmaxf(m, __shfl_xor(m, sh, 64));
    // pass 2: sum of exp
    float ls = 0.f;
    for (int j = s + lane; j < e; j += 64) {
        int ss = csr_src[j];
        float ev = a0x[ss] + a1n;
        ev = ev > 0.f ? ev : 0.2f * ev;
        ls += expf(ev - m);
    }
    #pragma unroll
    for (int sh = 32; sh; sh >>= 1) ls += __shfl_xor(ls, sh, 64);
    float sinv = 1.f / (ls + 1e-16f);
    // pass 3: feature aggregation; lane owns features 2*lane, 2*lane+1
    float2 as = {0.f, 0.f}, an = {0.f, 0.f}, aa = {0.f, 0.f};
    const float2* x2 = (const float2*)x;
    for (int j0 = s; j0 < e; j0 += 64) {
        int cnt = min(64, e - j0);
        int ss = (lane < cnt) ? csr_src[j0 + lane] : 0;
        float wn = dinv[ss] * dinvn;
        float ev = a0x[ss] + a1n;
        ev = ev > 0.f ? ev : 0.2f * ev;
        float wa = expf(ev - m) * sinv;
        for (int k = 0; k < cnt; ++k) {
            int sid  = __shfl(ss, k, 64);
            float wnk = __shfl(wn, k, 64);
            float wak = __shfl(wa, k, 64);
            float2 xv = x2[sid * 64 + lane];
            as.x += xv.x;        as.y += xv.y;
            an.x += wnk * xv.x;  an.y += wnk * xv.y;
            aa.x += wak * xv.x;  aa.y += wak * xv.y;
        }
    }
    float2 xv = x2[(size_t)n * 64 + lane];
    float inv_d = 1.f / degc[n];
    int idx = n * 64 + lane;
    An[idx]  = pack2(an.x, an.y);
    Axs[idx] = pack2(xv.x + as.x, xv.y + as.y);
    Aat[idx] = pack2(aa.x, aa.y);
    Axm[idx] = pack2(xv.x + as.x * inv_d, xv.y + as.y * inv_d);
    Am[idx]  = pack2(as.x * inv_d, as.y * inv_d);
    Ax[idx]  = pack2(xv.x, xv.y);
}

// ---- W_ops → fragment-ready bf16 layout: [l][o][ct][ks][lane][j] ----
__global__ void k_wprep(const float* __restrict__ Wops, unsigned short* __restrict__ wfrag) {
    int idx = blockIdx.x * 256 + threadIdx.x;
    if (idx >= LL * 114688) return;
    int l = idx / 114688, rem = idx % 114688;
    int o = rem / 16384; int r2 = rem % 16384;
    int ct = r2 >> 11; int ks = (r2 >> 9) & 3; int lane = (r2 >> 3) & 63; int j = r2 & 7;
    int h = ks * 32 + (lane >> 4) * 8 + j;
    int col = ct * 16 + (lane & 15);
    int c = col >> 5, kc = col & 31;
    float v = Wops[(((size_t)(l * CC + c) * OPS_ + o) * HH + h) * KK + kc];
    wfrag[idx] = f2bf(v);
}

// ---- bias reorder [l][o][col] + DARTS softmax mix weights [l][c][o] ----
__global__ void k_sprep(const float* __restrict__ bops, const float* __restrict__ alphas,
                        float* __restrict__ biasf, float* __restrict__ mixw) {
    int idx = blockIdx.x * 256 + threadIdx.x;
    if (idx < LL * OPS_ * HH) {
        int l = idx / 896; int rem = idx % 896;
        int o = rem / 128; int col = rem % 128;
        int c = col >> 5, kc = col & 31;
        biasf[idx] = bops[((l * CC + c) * OPS_ + o) * KK + kc];
    }
    if (idx < LL * CC) {
        int l = idx / CC, c = idx % CC;
        const float* a = alphas + (l * CC + c) * OPS_;
        float mx = -INFINITY;
        for (int o = 0; o < OPS_; ++o) mx = fmaxf(mx, a[o]);
        float s = 0.f, e[OPS_];
        for (int o = 0; o < OPS_; ++o) { e[o] = expf(a[o] - mx); s += e[o]; }
        for (int o = 0; o < OPS_; ++o) mixw[(l * CC + c) * OPS_ + o] = e[o] / s;
    }
}

// ---- MFMA op-mix GEMM + LN(K=32) + DARTS mix + BN partials ----
// 128 nodes/block, 4 waves, each wave 2 row-tiles of 16. B staged per-op in LDS.
__global__ __launch_bounds__(256, 3) void k_mixmm(
        const unsigned short* __restrict__ An, const unsigned short* __restrict__ Axs,
        const unsigned short* __restrict__ Aat, const unsigned short* __restrict__ Axm,
        const unsigned short* __restrict__ Am, const unsigned short* __restrict__ Ax,
        const unsigned short* __restrict__ wfrag, const float* __restrict__ biasf,
        const float* __restrict__ lng, const float* __restrict__ lnb,
        const float* __restrict__ mixw,
        float* __restrict__ xnew, float* __restrict__ bnstat) {
    __shared__ unsigned short sB[16384];   // 32 KB: per-op B stage; reused as C out-stage
    __shared__ float sS[HH], sQ[HH];
    int t = threadIdx.x, w = t >> 6, lane = t & 63;
    int m16 = lane & 15, quad = lane >> 4;
    if (t < HH) { sS[t] = 0.f; sQ[t] = 0.f; }
    int nw = blockIdx.x * 128 + w * 32;    // this wave's 32 nodes (2 tiles of 16)
    const unsigned short* Aops[OPS_] = {An, Axs, Aat, Axm, Am, An, Ax};
    size_t arow0 = (size_t)min(nw + m16, NN - 1) * HH;
    size_t arow1 = (size_t)min(nw + 16 + m16, NN - 1) * HH;
    float lngv[8], lnbv[8];
    #pragma unroll
    for (int ct = 0; ct < 8; ++ct) { lngv[ct] = lng[ct * 16 + m16]; lnbv[ct] = lnb[ct * 16 + m16]; }
    f32x4_t xacc[2][8];
    #pragma unroll
    for (int i = 0; i < 2; ++i)
        #pragma unroll
        for (int ct = 0; ct < 8; ++ct) xacc[i][ct] = (f32x4_t){0.f, 0.f, 0.f, 0.f};

    for (int o = 0; o < OPS_; ++o) {
        __syncthreads();
        {   // stage this op's B (32 KB) coalesced
            const uint4* gp = (const uint4*)(wfrag + o * 16384);
            uint4* s4 = (uint4*)sB;
            #pragma unroll
            for (int i = 0; i < 8; ++i) s4[t + 256 * i] = gp[t + 256 * i];
        }
        __syncthreads();
        const unsigned short* A = Aops[o];
        bf16x8_t a0[4], a1[4];
        #pragma unroll
        for (int ks = 0; ks < 4; ++ks) {
            a0[ks] = *(const bf16x8_t*)(A + arow0 + ks * 32 + quad * 8);
            a1[ks] = *(const bf16x8_t*)(A + arow1 + ks * 32 + quad * 8);
        }
        #pragma unroll
        for (int g = 0; g < 4; ++g) {       // 32-col LN cell = col-tiles 2g, 2g+1
            f32x4_t acc00 = {0.f,0.f,0.f,0.f}, acc01 = {0.f,0.f,0.f,0.f};
            f32x4_t acc10 = {0.f,0.f,0.f,0.f}, acc11 = {0.f,0.f,0.f,0.f};
            #pragma unroll
            for (int ks = 0; ks < 4; ++ks) {
                bf16x8_t b0 = *(const bf16x8_t*)(sB + (2 * g) * 2048 + ks * 512 + lane * 8);
                bf16x8_t b1 = *(const bf16x8_t*)(sB + (2 * g + 1) * 2048 + ks * 512 + lane * 8);
                acc00 = __builtin_amdgcn_mfma_f32_16x16x32_bf16(a0[ks], b0, acc00, 0, 0, 0);
                acc01 = __builtin_amdgcn_mfma_f32_16x16x32_bf16(a0[ks], b1, acc01, 0, 0, 0);
                acc10 = __builtin_amdgcn_mfma_f32_16x16x32_bf16(a1[ks], b0, acc10, 0, 0, 0);
                acc11 = __builtin_amdgcn_mfma_f32_16x16x32_bf16(a1[ks], b1, acc11, 0, 0, 0);
            }
            float wm = mixw[g * OPS_ + o];
            float bv0 = biasf[o * HH + 2 * g * 16 + m16];
            float bv1 = biasf[o * HH + (2 * g + 1) * 16 + m16];
            float wg0 = wm * lngv[2 * g], wg1 = wm * lngv[2 * g + 1];
            float wb0 = wm * lnbv[2 * g], wb1 = wm * lnbv[2 * g + 1];
            #pragma unroll
            for (int r = 0; r < 4; ++r) {
                float v0 = acc00[r] + bv0, v1 = acc01[r] + bv1;
                float s = v0 + v1, q = v0 * v0 + v1 * v1;
                s += __shfl_xor(s, 1); q += __shfl_xor(q, 1);
                s += __shfl_xor(s, 2); q += __shfl_xor(q, 2);
                s += __shfl_xor(s, 4); q += __shfl_xor(q, 4);
                s += __shfl_xor(s, 8); q += __shfl_xor(q, 8);
                float mu = s * (1.f / 32.f);
                float var = fmaxf(q * (1.f / 32.f) - mu * mu, 0.f);
                float rs = rsqrtf(var + 1e-5f);
                xacc[0][2 * g][r]     += (v0 - mu) * rs * wg0 + wb0;
                xacc[0][2 * g + 1][r] += (v1 - mu) * rs * wg1 + wb1;
            }
            #pragma unroll
            for (int r = 0; r < 4; ++r) {
                float v0 = acc10[r] + bv0, v1 = acc11[r] + bv1;
                float s = v0 + v1, q = v0 * v0 + v1 * v1;
                s += __shfl_xor(s, 1); q += __shfl_xor(q, 1);
                s += __shfl_xor(s, 2); q += __shfl_xor(q, 2);
                s += __shfl_xor(s, 4); q += __shfl_xor(q, 4);
                s += __shfl_xor(s, 8); q += __shfl_xor(q, 8);
                float mu = s * (1.f / 32.f);
                float var = fmaxf(q * (1.f / 32.f) - mu * mu, 0.f);
                float rs = rsqrtf(var + 1e-5f);
                xacc[1][2 * g][r]     += (v0 - mu) * rs * wg0 + wb0;
                xacc[1][2 * g + 1][r] += (v1 - mu) * rs * wg1 + wb1;
            }
        }
    }
    // BN partial stats from registers
    #pragma unroll
    for (int ct = 0; ct < 8; ++ct) {
        float ps = 0.f, pq = 0.f;
        #pragma unroll
        for (int tile = 0; tile < 2; ++tile)
            #pragma unroll
            for (int r = 0; r < 4; ++r) {
                int n = nw + tile * 16 + quad * 4 + r;
                if (n < NN) { float v = xacc[tile][ct][r]; ps += v; pq += v * v; }
            }
        atomicAdd(&sS[ct * 16 + m16], ps);
        atomicAdd(&sQ[ct * 16 + m16], pq);
    }
    __syncthreads();   // all sB reads + sS/sQ atomics complete
    if (t < HH) { atomicAdd(&bnstat[t], sS[t]); atomicAdd(&bnstat[HH + t], sQ[t]); }
    // out-stage: per-wave 8 KB region of sB, transpose C-layout -> coalesced float4
    float* so = (float*)sB + w * 2048;
    for (int tile = 0; tile < 2; ++tile) {
        #pragma unroll
        for (int ct = 0; ct < 8; ++ct)
            #pragma unroll
            for (int r = 0; r < 4; ++r)
                so[(quad * 4 + r) * 128 + ct * 16 + m16] = xacc[tile][ct][r];
        #pragma unroll
        for (int i = 0; i < 8; ++i) {
            int flat = i * 256 + lane * 4;
            int row = flat >> 7, col = flat & 127;
            int n = nw + tile * 16 + row;
            float4 v = *(float4*)&so[flat];
            if (n < NN) *(float4*)&xnew[(size_t)n * HH + col] = v;
        }
    }
}

// ---------------- BN finalize (scale/shift per feature) ----------------
__global__ void k_bnfin(const float* __restrict__ stat, const float* __restrict__ g,
                        const float* __restrict__ b, float* __restrict__ scsh,
                        float invn, int dim) {
    int t = threadIdx.x;
    if (t < dim) {
        float mean = stat[t] * invn;
        float var = fmaxf(stat[dim + t] * invn - mean * mean, 0.f);
        float sc = g[t] * rsqrtf(var + 1e-5f);
        scsh[t] = sc;
        scsh[dim + t] = b[t] - mean * sc;
    }
}

// ---- BN apply + per-graph pool (mean/max) + graph sum -------------------
// 256 threads = 2 row-groups x 128 features; rows of the graph split in half
// across groups, merged via LDS (deterministic, no atomics).
__global__ __launch_bounds__(256) void k_pool(const float* __restrict__ src,
                                              const float* __restrict__ scsh,
                                              const int* __restrict__ goff,
                                              float* __restrict__ xout,
                                              float* __restrict__ pooled,
                                              float* __restrict__ gsum, int slice) {
    __shared__ float s1[HH], m1[HH];
    int b = blockIdx.x;
    int f = threadIdx.x & (HH - 1);
    int g = threadIdx.x >> 7;          // row-group 0/1
    int s = goff[b], e = goff[b + 1];
    int cnt = e - s;
    int half = (cnt + 1) >> 1;
    int rs = s + g * half;
    int re = min(e, rs + half);
    float sc = 1.f, sh = 0.f;
    if (scsh) { sc = scsh[f]; sh = scsh[HH + f]; }
    float fs = 0.f, fm = -INFINITY;
    for (int i = rs; i < re; ++i) {
        float v = src[i * HH + f] * sc + sh;
        if (xout) xout[i * HH + f] = v;
        fs += v;
        fm = fmaxf(fm, v);
    }
    if (g == 0) { s1[f] = fs; m1[f] = fm; }
    __syncthreads();
    if (g == 1) {
        fs += s1[f];
        fm = fmaxf(fm, m1[f]);
        float c = fmaxf((float)cnt, 1.f);
        pooled[b * DD + slice * HH + f] = fs / c;
        pooled[b * DD + 512 + slice * HH + f] = (cnt > 0) ? fm : 0.f;
        if (gsum) gsum[b * HH + f] = fs;
    }
}

// ---------------- virtual-node MLP pieces ----------------
__global__ void k_vn1(const float* __restrict__ gsum, const float* __restrict__ vn,
                      const float* __restrict__ W1, const float* __restrict__ b1,
                      float* __restrict__ h1, float* __restrict__ stat) {
    __shared__ float row[HH];
    int b = blockIdx.x, t = threadIdx.x;   // 256 threads
    if (t < HH) row[t] = gsum[b * HH + t] + vn[b * HH + t];
    __syncthreads();
    float acc = b1[t];
    for (int h = 0; h < HH; ++h) acc += row[h] * W1[h * 2 * HH + t];
    h1[b * 2 * HH + t] = acc;
    atomicAdd(&stat[t], acc);
    atomicAdd(&stat[2 * HH + t], acc * acc);
}

__global__ void k_vn2(const float* __restrict__ h1, const float* __restrict__ scsh1,
                      const float* __restrict__ W2, const float* __restrict__ b2,
                      float* __restrict__ h2, float* __restrict__ stat) {
    __shared__ float row[2 * HH];
    int b = blockIdx.x, t = threadIdx.x;   // 256 threads
    float v = h1[b * 2 * HH + t] * scsh1[t] + scsh1[2 * HH + t];
    row[t] = fmaxf(v, 0.f);
    __syncthreads();
    if (t < HH) {
        float acc = b2[t];
        for (int h = 0; h < 2 * HH; ++h) acc += row[h] * W2[h * HH + t];
        h2[b * HH + t] = acc;
        atomicAdd(&stat[t], acc);
        atomicAdd(&stat[HH + t], acc * acc);
    }
}

__global__ void k_vnout(const float* __restrict__ h2, const float* __restrict__ scsh2,
                        float* __restrict__ vn) {
    int i = blockIdx.x * 256 + threadIdx.x;
    if (i < BB * HH) {
        int f = i & (HH - 1);
        float v = h2[i] * scsh2[f] + scsh2[HH + f];
        vn[i] = fmaxf(v, 0.f);
    }
}

// ---------------- masked head ----------------
__global__ void k_head(const float* __restrict__ pooled, const float* __restrict__ W,
                       const float* __restrict__ bias, const float* __restrict__ mask,
                       float* __restrict__ out) {
    int wave = threadIdx.x >> 6, lane = threadIdx.x & 63;
    int idx = blockIdx.x * 4 + wave;
    if (idx >= BB * OUTD) return;
    int b = idx / OUTD, o = idx % OUTD;
    float acc = 0.f;
    for (int k = lane; k < DD; k += 64)
        acc += pooled[b * DD + k] * W[k * OUTD + o] * mask[k * OUTD + o];
    #pragma unroll
    for (int sh = 32; sh; sh >>= 1) acc += __shfl_xor(acc, sh, 64);
    if (lane == 0) out[idx] = acc + bias[o];
}

extern "C" void kernel_launch(void* const* d_in, const int* in_sizes, int n_in,
                              void* d_out, int out_size, void* d_ws, size_t ws_size,
                              hipStream_t stream) {
    const float* x_in   = (const float*)d_in[0];
    const int*   ei     = (const int*)d_in[1];
    const int*   batch  = (const int*)d_in[2];
    const float* lin1W  = (const float*)d_in[3];
    const float* lin1b  = (const float*)d_in[4];
    const float* vn0    = (const float*)d_in[5];
    const float* Wops   = (const float*)d_in[6];
    const float* bops   = (const float*)d_in[7];
    const float* atta   = (const float*)d_in[8];
    const float* lng    = (const float*)d_in[9];
    const float* lnb    = (const float*)d_in[10];
    const float* bng    = (const float*)d_in[11];
    const float* bnb    = (const float*)d_in[12];
    const float* vnW1   = (const float*)d_in[13];
    const float* vnb1   = (const float*)d_in[14];
    const float* vnbn1g = (const float*)d_in[15];
    const float* vnbn1b = (const float*)d_in[16];
    const float* vnW2   = (const float*)d_in[17];
    const float* vnb2   = (const float*)d_in[18];
    const float* vnbn2g = (const float*)d_in[19];
    const float* vnbn2b = (const float*)d_in[20];
    const float* alphas = (const float*)d_in[21];
    const float* headW  = (const float*)d_in[22];
    const float* headb  = (const float*)d_in[23];
    const float* headm  = (const float*)d_in[24];
    float* out = (float*)d_out;
    const int* src = ei;
    const int* dst = ei + EE;

    // ---- workspace layout (fp32 words) ----
    float* ws = (float*)d_ws;
    size_t p = 0;
    float* xcur    = ws + p; p += (size_t)NN * HH;
    float* a0x     = ws + p; p += NN;
    float* a1x     = ws + p; p += NN;
    float* degc    = ws + p; p += NN;
    float* dinv    = ws + p; p += NN;
    float* vn      = ws + p; p += BB * HH;
    float* gsum    = ws + p; p += BB * HH;
    float* h1      = ws + p; p += BB * 2 * HH;
    float* h2      = ws + p; p += BB * HH;
    float* pooled  = ws + p; p += (size_t)BB * DD;
    float* bnscsh  = ws + p; p += LL * 2 * HH;
    float* vnsc1   = ws + p; p += 2 * 2 * (2 * HH);
    float* vnsc2   = ws + p; p += 2 * 2 * HH;
    float* biasf   = ws + p; p += LL * OPS_ * HH;
    float* mixw    = ws + p; p += LL * CC * OPS_;
    // bf16 op-input matrices: 6 x [NN][128] bf16, addressed as uint (2 bf16 each)
    unsigned int* An  = (unsigned int*)(ws + p); p += (size_t)NN * 64;
    unsigned int* Axs = (unsigned int*)(ws + p); p += (size_t)NN * 64;
    unsigned int* Aat = (unsigned int*)(ws + p); p += (size_t)NN * 64;
    unsigned int* Axm = (unsigned int*)(ws + p); p += (size_t)NN * 64;
    unsigned int* Am  = (unsigned int*)(ws + p); p += (size_t)NN * 64;
    unsigned int* Ax  = (unsigned int*)(ws + p); p += (size_t)NN * 64;
    unsigned short* wfrag = (unsigned short*)(ws + p); p += (LL * 114688) / 2;
    // zeroed float region (atomic accumulators)
    float* zf = ws + p;
    float* bnstat  = ws + p; p += LL * 2 * HH;          // 768
    float* vnstat1 = ws + p; p += 2 * 2 * (2 * HH);     // 1024
    float* vnstat2 = ws + p; p += 2 * 2 * HH;           // 512
    size_t zf_cnt = (size_t)((ws + p) - zf);
    // int region
    int* ib = (int*)(ws + p);
    int* deg    = ib;                 // zeroed
    int* gcount = ib + NN;            // zeroed
    int* cursor = ib + NN + 1;        // zeroed
    size_t zi_cnt = (size_t)(2 * NN + 1);
    int* off    = ib + 2 * NN + 1;
    int* goff   = off + NN;
    int* csr    = goff + (BB + 1);

    hipMemsetAsync(zf, 0, zf_cnt * sizeof(float), stream);
    hipMemsetAsync(ib, 0, zi_cnt * sizeof(int), stream);

    // ---- graph/CSR setup + weight prep ----
    k_lin1<<<(NN + 63) / 64, 256, 0, stream>>>(x_in, lin1W, lin1b, xcur);
    k_deg<<<(EE + 255) / 256, 256, 0, stream>>>(dst, deg);
    k_alloc<<<(NN + 255) / 256, 256, 0, stream>>>(deg, off, gcount, degc, dinv);
    k_csrfill<<<(EE + 255) / 256, 256, 0, stream>>>(src, dst, off, cursor, csr);
    k_goff<<<(NN + 255) / 256, 256, 0, stream>>>(batch, goff);
    k_vninit<<<(BB * HH + 255) / 256, 256, 0, stream>>>(vn0, vn);
    k_wprep<<<(LL * 114688 + 255) / 256, 256, 0, stream>>>(Wops, wfrag);
    k_sprep<<<(LL * OPS_ * HH + 255) / 256, 256, 0, stream>>>(bops, alphas, biasf, mixw);
    // pool slice 0 (gr[0] = elu(lin1) x, pre-vn)
    k_pool<<<BB, 256, 0, stream>>>(xcur, nullptr, goff, nullptr, pooled, nullptr, 0);

    for (int l = 0; l < LL; ++l) {
        k_addvn_dots<<<NN / 4, 256, 0, stream>>>(xcur, vn, batch, atta + l * 2 * HH, a0x, a1x);
        k_agg<<<NN / 4, 256, 0, stream>>>(xcur, off, deg, csr, dinv, degc, a0x, a1x,
                                          An, Axs, Aat, Axm, Am, Ax);
        k_mixmm<<<(NN + 127) / 128, 256, 0, stream>>>(
            (const unsigned short*)An, (const unsigned short*)Axs,
            (const unsigned short*)Aat, (const unsigned short*)Axm,
            (const unsigned short*)Am, (const unsigned short*)Ax,
            wfrag + (size_t)l * 114688, biasf + l * OPS_ * HH,
            lng + l * HH, lnb + l * HH, mixw + l * CC * OPS_,
            xcur, bnstat + l * 2 * HH);
        k_bnfin<<<1, 128, 0, stream>>>(bnstat + l * 2 * HH, bng + l * HH, bnb + l * HH,
                                       bnscsh + l * 2 * HH, 1.0f / (float)NN, HH);
        k_pool<<<BB, 256, 0, stream>>>(xcur, bnscsh + l * 2 * HH, goff, xcur, pooled,
                                       (l < LL - 1) ? gsum : nullptr, l + 1);
        if (l < LL - 1) {
            k_vn1<<<BB, 256, 0, stream>>>(gsum, vn, vnW1 + (size_t)l * HH * 2 * HH,
                                          vnb1 + l * 2 * HH, h1, vnstat1 + l * 2 * (2 * HH));
            k_bnfin<<<1, 256, 0, stream>>>(vnstat1 + l * 2 * (2 * HH), vnbn1g + l * 2 * HH,
                                           vnbn1b + l * 2 * HH, vnsc1 + l * 2 * (2 * HH),
                                           1.0f / (float)BB, 2 * HH);
            k_vn2<<<BB, 256, 0, stream>>>(h1, vnsc1 + l * 2 * (2 * HH),
                                          vnW2 + (size_t)l * 2 * HH * HH, vnb2 + l * HH,
                                          h2, vnstat2 + l * 2 * HH);
            k_bnfin<<<1, 128, 0, stream>>>(vnstat2 + l * 2 * HH, vnbn2g + l * HH,
                                           vnbn2b + l * HH, vnsc2 + l * 2 * HH,
                                           1.0f / (float)BB, HH);
            k_vnout<<<(BB * HH + 255) / 256, 256, 0, stream>>>(h2, vnsc2 + l * 2 * HH, vn);
        }
    }
    k_head<<<(BB * OUTD) / 4, 256, 0, stream>>>(pooled, headW, headb, headm, out);
}